// Round 25
// baseline (314.890 us; speedup 1.0000x reference)
//
#include <hip/hip_runtime.h>
#include <math.h>

#define NODES 50000
#define NEDGE 400000
#define ETOT  450000   // NEDGE + NODES self loops
#define DIN   256
#define C1    256      // heads*dh = 8*32
#define C2    40
#define CPAD  64                        // ELL row pitch (max degree ~25 for this graph)
#define CSRCAP (NODES * CPAD)           // 3.2M slots
#define NB_CNT ((ETOT + 255) / 256)     // 1758 place blocks
#define NB_CVT (NODES * DIN / 8 / 256)  // 6250 cvt blocks

typedef __attribute__((ext_vector_type(8))) short bfrag;
typedef __attribute__((ext_vector_type(4))) float facc;

#define GPTR(p) (const __attribute__((address_space(1))) unsigned int*)(p)
#define LPTR(p) (__attribute__((address_space(3))) unsigned int*)(p)

static __device__ __forceinline__ float bitsf(unsigned int x) {
    float f;
    __builtin_memcpy(&f, &x, 4);
    return f;
}
static __device__ __forceinline__ unsigned short f2bf(float f) {
    unsigned int x;
    __builtin_memcpy(&x, &f, 4);
    unsigned int r = x + 0x7fffu + ((x >> 16) & 1u);   // RNE
    return (unsigned short)(r >> 16);
}
static __device__ __forceinline__ float fexp2(float x) {
#if __has_builtin(__builtin_amdgcn_exp2f)
    return __builtin_amdgcn_exp2f(x);
#else
    return exp2f(x);
#endif
}

// ---------------- fused prep A: ELL place (count+scatter) + x f32->bf16 convert ----------------
__global__ __launch_bounds__(256)
void prep_a(const int* __restrict__ srcRow, const int* __restrict__ dstRow,
            int* __restrict__ cnt, int* __restrict__ csr,
            const float* __restrict__ x, unsigned short* __restrict__ xb)
{
    if (blockIdx.x < NB_CNT) {
        int e = blockIdx.x * 256 + threadIdx.x;
        if (e >= ETOT) return;
        int d, s;
        if (e < NEDGE) { d = dstRow[e]; s = srcRow[e]; }
        else           { d = e - NEDGE; s = d; }
        int slot = atomicAdd(&cnt[d], 1);
        csr[(d << 6) + slot] = s;
    } else {
        int i = (blockIdx.x - NB_CNT) * 256 + threadIdx.x;   // < NB_CVT*256 exactly
        const float4* p = (const float4*)x + (size_t)i * 2;
        float4 u0 = p[0], u1 = p[1];
        bfrag pk;
        pk[0] = (short)f2bf(u0.x); pk[1] = (short)f2bf(u0.y);
        pk[2] = (short)f2bf(u0.z); pk[3] = (short)f2bf(u0.w);
        pk[4] = (short)f2bf(u1.x); pk[5] = (short)f2bf(u1.y);
        pk[6] = (short)f2bf(u1.z); pk[7] = (short)f2bf(u1.w);
        *(bfrag*)(xb + (size_t)i * 8) = pk;
    }
}

// ---------------- fused prep W: both weight transposes ----------------
__global__ __launch_bounds__(256)
void prep_ww(const float* __restrict__ W1l, const float* __restrict__ W1r,
             unsigned short* __restrict__ Wt1,
             const float* __restrict__ W2l, const float* __restrict__ W2r,
             unsigned short* __restrict__ Wt2)
{
    if (blockIdx.x < 512) {
        const int idx = blockIdx.x * 256 + threadIdx.x;   // n*256 + k
        const int n = idx >> 8;
        const int k = idx & 255;
        float v = (n < C1) ? W1l[(size_t)k * C1 + n] : W1r[(size_t)k * C1 + (n - C1)];
        Wt1[idx] = f2bf(v);
    } else {
        const int idx = (blockIdx.x - 512) * 256 + threadIdx.x;
        const int n = idx >> 8;
        const int k = idx & 255;
        if (n >= 2 * C2) return;
        float v = (n < C2) ? W2l[(size_t)k * C2 + n] : W2r[(size_t)k * C2 + (n - C2)];
        Wt2[idx] = f2bf(v);
    }
}

// ---------------- MFMA dual GEMM: 3-buffer / 2-ahead pipeline, 1 barrier per K-step ----------------
#define GBM 128
#define GBN 128
#define GBK 32

template<typename OUTT, bool SWZ>
__global__ __launch_bounds__(256)
void mfma_gemm(const unsigned short* __restrict__ Ab, const unsigned short* __restrict__ Bt,
               const float* __restrict__ bl, const float* __restrict__ br,
               OUTT* __restrict__ Cl, OUTT* __restrict__ Cr,
               int M, int Nrows, int Nhalf, int nbnShift)
{
    __shared__ __align__(16) unsigned short As[3][GBM * GBK];
    __shared__ __align__(16) unsigned short Bs[3][GBN * GBK];

    const int tid  = threadIdx.x;
    const int lane = tid & 63;
    const int w    = tid >> 6;
    const int wr   = w >> 1;
    const int wc   = w & 1;

    int tile;
    if constexpr (SWZ) {
        const int nwg = gridDim.x;
        const int q = nwg >> 3, r = nwg & 7;
        const int xcd = blockIdx.x & 7;
        const int idx = blockIdx.x >> 3;
        tile = (xcd < r ? xcd * (q + 1) : r * (q + 1) + (xcd - r) * q) + idx;
    } else {
        tile = blockIdx.x;
    }
    const int bx   = tile >> nbnShift;
    const int by   = tile & ((1 << nbnShift) - 1);
    const int row0 = bx * GBM;
    const int col0 = by * GBN;

    facc acc[4][4];
    #pragma unroll
    for (int i = 0; i < 4; ++i)
        #pragma unroll
        for (int j = 0; j < 4; ++j) {
            facc z = {0.f, 0.f, 0.f, 0.f};
            acc[i][j] = z;
        }

    const int rA  = lane >> 2;
    const int kgA = (lane & 3) ^ ((rA >> 1) & 3);
    const int fr    = lane & 15;
    const int sRead = (lane >> 4) ^ ((fr >> 1) & 3);

    #define STAGE(bufi, k0)                                                     \
    {                                                                           \
        _Pragma("unroll")                                                       \
        for (int p = 0; p < 2; ++p) {                                           \
            const int chunk = p * 4 + w;                                        \
            const int r_loc = chunk * 16 + rA;                                  \
            const int ga = min(row0 + r_loc, M - 1);                            \
            __builtin_amdgcn_global_load_lds(                                   \
                GPTR(Ab + (size_t)ga * 256 + (k0) + kgA * 8),                   \
                LPTR(&As[bufi][chunk * 512]), 16, 0, 0);                        \
            const int gb = min(col0 + r_loc, Nrows - 1);                        \
            __builtin_amdgcn_global_load_lds(                                   \
                GPTR(Bt + (size_t)gb * 256 + (k0) + kgA * 8),                   \
                LPTR(&Bs[bufi][chunk * 512]), 16, 0, 0);                        \
        }                                                                       \
    }

    #define KSTEP(T, WSTR)                                                      \
    {                                                                           \
        asm volatile("s_waitcnt vmcnt(" WSTR ")" ::: "memory");                 \
        __builtin_amdgcn_s_barrier();                                           \
        __builtin_amdgcn_sched_barrier(0);                                      \
        constexpr int cur = (T) % 3;                                            \
        bfrag af[4], bfv[4];                                                    \
        _Pragma("unroll")                                                       \
        for (int mi = 0; mi < 4; ++mi)                                          \
            af[mi] = *(const bfrag*)(&As[cur][(wr * 64 + mi * 16 + fr) * 32 + sRead * 8]); \
        _Pragma("unroll")                                                       \
        for (int ni = 0; ni < 4; ++ni)                                          \
            bfv[ni] = *(const bfrag*)(&Bs[cur][(wc * 64 + ni * 16 + fr) * 32 + sRead * 8]); \
        if constexpr ((T) + 2 < 8) STAGE(((T) + 2) % 3, ((T) + 2) * GBK);       \
        _Pragma("unroll")                                                       \
        for (int mi = 0; mi < 4; ++mi)                                          \
            _Pragma("unroll")                                                   \
            for (int ni = 0; ni < 4; ++ni)                                      \
                acc[mi][ni] = __builtin_amdgcn_mfma_f32_16x16x32_bf16(          \
                    af[mi], bfv[ni], acc[mi][ni], 0, 0, 0);                     \
    }

    STAGE(0, 0 * GBK);
    STAGE(1, 1 * GBK);
    KSTEP(0, "4"); KSTEP(1, "4"); KSTEP(2, "4"); KSTEP(3, "4");
    KSTEP(4, "4"); KSTEP(5, "4"); KSTEP(6, "4"); KSTEP(7, "0");
    #undef KSTEP
    #undef STAGE

    #pragma unroll
    for (int mi = 0; mi < 4; ++mi) {
        const int rbase = row0 + wr * 64 + mi * 16 + ((lane >> 4) << 2);
        #pragma unroll
        for (int ni = 0; ni < 4; ++ni) {
            const int col = col0 + wc * 64 + ni * 16 + (lane & 15);
            #pragma unroll
            for (int rg = 0; rg < 4; ++rg) {
                int r = rbase + rg;
                if (r >= M) continue;
                float v = acc[mi][ni][rg];
                if (col < Nhalf) {
                    v += bl[col];
                    if constexpr (sizeof(OUTT) == 2)
                        Cl[(size_t)r * Nhalf + col] = (OUTT)f2bf(v);
                    else
                        Cl[(size_t)r * Nhalf + col] = (OUTT)v;
                } else if (col < 2 * Nhalf) {
                    int c2 = col - Nhalf;
                    v += br[c2];
                    if constexpr (sizeof(OUTT) == 2)
                        Cr[(size_t)r * Nhalf + c2] = (OUTT)f2bf(v);
                    else
                        Cr[(size_t)r * Nhalf + c2] = (OUTT)v;
                }
            }
        }
    }
}

// ---------------- fused layer 1: wave/node, 2 edges per wave (half-wave split) ----------------
// lane owns 8 channels (4 lanes per head); halves process disjoint edges; merged at end.
// logit dot split into 2 partial sums (chain depth 8, 4 independent chains/iteration)
__global__ __launch_bounds__(256, 8)
void fused_l1(const int* __restrict__ deg,
              const int* __restrict__ csr, const unsigned short* __restrict__ xl,
              const unsigned short* __restrict__ xr, const float* __restrict__ att,
              const float* __restrict__ bias, unsigned short* __restrict__ hout)
{
    const int lane = threadIdx.x & 63;
    const int n    = blockIdx.x * 4 + (threadIdx.x >> 6);
    if (n >= NODES) return;
    const int eh  = lane >> 5;    // edge half (0/1)
    const int l32 = lane & 31;
    const int c0  = l32 * 8;      // channel base (8 channels/lane, 4 lanes/head)

    const int a  = n << 6;        // ELL base
    const int dn = __builtin_amdgcn_readfirstlane(deg[n]);
    const int np = (dn + 3) & ~3;

    const float L2E = 1.4426950408889634f;
    const float MINIT = -1e30f, MMASK = -2e30f;   // finite sentinels (exp2 diff underflows to 0)

    float xrv[8];
    {
        const uint4 u = *(const uint4*)(xr + (size_t)n * C1 + c0);
        xrv[0] = bitsf(u.x << 16); xrv[1] = bitsf(u.x & 0xffff0000u);
        xrv[2] = bitsf(u.y << 16); xrv[3] = bitsf(u.y & 0xffff0000u);
        xrv[4] = bitsf(u.z << 16); xrv[5] = bitsf(u.z & 0xffff0000u);
        xrv[6] = bitsf(u.w << 16); xrv[7] = bitsf(u.w & 0xffff0000u);
    }
    float w6[8], w4[8];
    {
        const float4 wa = *(const float4*)(att + c0);
        const float4 wb = *(const float4*)(att + c0 + 4);
        const float wv[8] = {wa.x, wa.y, wa.z, wa.w, wb.x, wb.y, wb.z, wb.w};
        #pragma unroll
        for (int j = 0; j < 8; ++j) {
            w6[j] = wv[j] * (0.6f * L2E);
            w4[j] = wv[j] * (0.4f * L2E);
        }
    }

    float m = MINIT, d = 0.f;
    float acc[8] = {0.f, 0.f, 0.f, 0.f, 0.f, 0.f, 0.f, 0.f};

    // each half-lane loads its 2 edges' src (int2) + 2 row slices (uint4)
    #define LOADG(D0, D1, I)                                                     \
    {                                                                            \
        const int2 s2 = *(const int2*)(csr + a + (I) + 2 * eh);                  \
        D0 = *(const uint4*)(xl + (size_t)s2.x * C1 + c0);                       \
        D1 = *(const uint4*)(xl + (size_t)s2.y * C1 + c0);                       \
    }
    #define UNPACK(X, U)                                                         \
        X[0] = bitsf(U.x << 16); X[1] = bitsf(U.x & 0xffff0000u);                \
        X[2] = bitsf(U.y << 16); X[3] = bitsf(U.y & 0xffff0000u);                \
        X[4] = bitsf(U.z << 16); X[5] = bitsf(U.z & 0xffff0000u);                \
        X[6] = bitsf(U.w << 16); X[7] = bitsf(U.w & 0xffff0000u);

    uint4 R0, R1;
    LOADG(R0, R1, 0);

    for (int i = 0; i < np; i += 4) {
        uint4 Rn0, Rn1;
        LOADG(Rn0, Rn1, i + 4);   // indices <= i+4+3 <= 31 < CPAD; pads zeroed

        float x0[8], x1[8];
        UNPACK(x0, R0)
        UNPACK(x1, R1)

        // logit dot products: 2 partial sums each (chain depth 8 -> better ILP)
        float p0a = 0.f, p0b = 0.f, p1a = 0.f, p1b = 0.f;
        #pragma unroll
        for (int j = 0; j < 4; ++j) {
            const float v = x0[j] + xrv[j];
            p0a = fmaf(w6[j], v, p0a);
            p0a = fmaf(w4[j], fabsf(v), p0a);
        }
        #pragma unroll
        for (int j = 4; j < 8; ++j) {
            const float v = x0[j] + xrv[j];
            p0b = fmaf(w6[j], v, p0b);
            p0b = fmaf(w4[j], fabsf(v), p0b);
        }
        #pragma unroll
        for (int j = 0; j < 4; ++j) {
            const float v = x1[j] + xrv[j];
            p1a = fmaf(w6[j], v, p1a);
            p1a = fmaf(w4[j], fabsf(v), p1a);
        }
        #pragma unroll
        for (int j = 4; j < 8; ++j) {
            const float v = x1[j] + xrv[j];
            p1b = fmaf(w6[j], v, p1b);
            p1b = fmaf(w4[j], fabsf(v), p1b);
        }
        float p0 = p0a + p0b;
        float p1 = p1a + p1b;
        p0 += __shfl_xor(p0, 1); p0 += __shfl_xor(p0, 2);
        p1 += __shfl_xor(p1, 1); p1 += __shfl_xor(p1, 2);
        const int e0 = i + 2 * eh;
        p0 = (e0     < dn) ? p0 : MMASK;
        p1 = (e0 + 1 < dn) ? p1 : MMASK;

        const float pm = fmaxf(p0, p1);
        if (__any(pm > m + 8.f)) {
            float mN = fmaxf(m, p0);
            float sc = fexp2(m - mN);
            float wg = fexp2(p0 - mN);
            m = mN;
            d = fmaf(d, sc, wg);
            #pragma unroll
            for (int j = 0; j < 8; ++j) acc[j] = fmaf(wg, x0[j], acc[j] * sc);
            mN = fmaxf(m, p1);
            sc = fexp2(m - mN);
            wg = fexp2(p1 - mN);
            m = mN;
            d = fmaf(d, sc, wg);
            #pragma unroll
            for (int j = 0; j < 8; ++j) acc[j] = fmaf(wg, x1[j], acc[j] * sc);
        } else {
            const float wg0 = fexp2(p0 - m);
            const float wg1 = fexp2(p1 - m);
            d += wg0 + wg1;
            #pragma unroll
            for (int j = 0; j < 8; ++j)
                acc[j] = fmaf(wg1, x1[j], fmaf(wg0, x0[j], acc[j]));
        }

        R0 = Rn0; R1 = Rn1;
    }
    #undef LOADG
    #undef UNPACK

    // merge the two halves (same channels, disjoint edges)
    {
        const float mo = __shfl_xor(m, 32);
        const float mN = fmaxf(m, mo);
        const float sc = fexp2(m - mN);   // underflows to 0 for an all-masked half
        d *= sc;
        d += __shfl_xor(d, 32);
        #pragma unroll
        for (int j = 0; j < 8; ++j) {
            acc[j] *= sc;
            acc[j] += __shfl_xor(acc[j], 32);
        }
    }

    const float inv = 1.f / d;
    float vv[8];
    {
        const float4 ba = *(const float4*)(bias + c0);
        const float4 bb = *(const float4*)(bias + c0 + 4);
        const float bv[8] = {ba.x, ba.y, ba.z, ba.w, bb.x, bb.y, bb.z, bb.w};
        #pragma unroll
        for (int j = 0; j < 8; ++j) {
            float v = fmaf(acc[j], inv, bv[j]);
            vv[j] = v > 0.f ? v : (fexp2(v * L2E) - 1.f);
        }
    }
    if (eh == 0) {
        uint4 o;
        o.x = (unsigned int)f2bf(vv[0]) | ((unsigned int)f2bf(vv[1]) << 16);
        o.y = (unsigned int)f2bf(vv[2]) | ((unsigned int)f2bf(vv[3]) << 16);
        o.z = (unsigned int)f2bf(vv[4]) | ((unsigned int)f2bf(vv[5]) << 16);
        o.w = (unsigned int)f2bf(vv[6]) | ((unsigned int)f2bf(vv[7]) << 16);
        *(uint4*)(hout + (size_t)n * C1 + c0) = o;
    }
}

// ---------------- fused layer 2: 8-edge groups + prefetch, ELL base = n*64 ----------------
__global__ __launch_bounds__(256)
void fused_l2(const int* __restrict__ deg,
              const int* __restrict__ csr, const float* __restrict__ h2l,
              const float* __restrict__ h2r, const float* __restrict__ att,
              const float* __restrict__ bias, float* __restrict__ out)
{
    const int lane = threadIdx.x & 63;
    const int n    = blockIdx.x * 4 + (threadIdx.x >> 6);
    if (n >= NODES) return;
    const int l8 = lane & 7;
    const int g  = lane >> 3;

    const int a  = n << 6;   // ELL base
    const int dn = __builtin_amdgcn_readfirstlane(deg[n]);
    const float L2E = 1.4426950408889634f;

    float w6[5], w4[5], xr[5];
    #pragma unroll
    for (int j = 0; j < 5; ++j) {
        const int c = l8 + 8 * j;
        const float w = att[c];
        w6[j] = w * (0.6f * L2E);
        w4[j] = w * (0.4f * L2E);
        xr[j] = h2r[(size_t)n * C2 + c];
    }

    float m = -INFINITY, dl = 0.f;
    float acc[5] = {0.f, 0.f, 0.f, 0.f, 0.f};

    // prologue: load chunk 0
    float R[5];
    {
        const int src = csr[a + g];
        const float* row = h2l + (size_t)src * C2 + l8;
        #pragma unroll
        for (int j = 0; j < 5; ++j) R[j] = row[8 * j];
    }

    for (int c0 = 0; c0 < dn; c0 += 8) {
        // prefetch chunk c0+8 (pad slots zeroed; c0+8+g <= 40 < CPAD)
        float Rn[5];
        {
            const int nx = (c0 + 8 < dn) ? (c0 + 8) : c0;
            const int src = csr[a + nx + g];
            const float* row = h2l + (size_t)src * C2 + l8;
            #pragma unroll
            for (int j = 0; j < 5; ++j) Rn[j] = row[8 * j];
        }

        const int idx = c0 + g;
        float p = 0.f;
        #pragma unroll
        for (int j = 0; j < 5; ++j) {
            const float v = R[j] + xr[j];
            p = fmaf(w6[j], v, p);
            p = fmaf(w4[j], fabsf(v), p);
        }
        p += __shfl_xor(p, 1);
        p += __shfl_xor(p, 2);
        p += __shfl_xor(p, 4);
        if (idx >= dn) p = -INFINITY;

        if (__any(p > m + 8.f)) {
            float pm = p;
            pm = fmaxf(pm, __shfl_xor(pm, 8));
            pm = fmaxf(pm, __shfl_xor(pm, 16));
            pm = fmaxf(pm, __shfl_xor(pm, 32));
            const float mN = fmaxf(m, pm);
            const float sc = fexp2(m - mN);
            const float wg = fexp2(p - mN);
            m = mN;
            dl = fmaf(dl, sc, wg);
            #pragma unroll
            for (int j = 0; j < 5; ++j) acc[j] = fmaf(wg, R[j], acc[j] * sc);
        } else {
            const float wg = fexp2(p - m);
            dl += wg;
            #pragma unroll
            for (int j = 0; j < 5; ++j) acc[j] = fmaf(wg, R[j], acc[j]);
        }

        #pragma unroll
        for (int j = 0; j < 5; ++j) R[j] = Rn[j];
    }

    #pragma unroll
    for (int o = 8; o < 64; o <<= 1) {
        dl += __shfl_xor(dl, o);
        #pragma unroll
        for (int j = 0; j < 5; ++j) acc[j] += __shfl_xor(acc[j], o);
    }

    const float inv = 1.f / dl;
    float v[5];
    float mx = -INFINITY;
    #pragma unroll
    for (int j = 0; j < 5; ++j) {
        v[j] = fmaf(acc[j], inv, bias[l8 + 8 * j]);
        mx = fmaxf(mx, v[j]);
    }
    mx = fmaxf(mx, __shfl_xor(mx, 1));
    mx = fmaxf(mx, __shfl_xor(mx, 2));
    mx = fmaxf(mx, __shfl_xor(mx, 4));
    float s = 0.f;
    #pragma unroll
    for (int j = 0; j < 5; ++j) s += fexp2((v[j] - mx) * L2E);
    s += __shfl_xor(s, 1);
    s += __shfl_xor(s, 2);
    s += __shfl_xor(s, 4);
    const float lg = logf(s);
    if (g == 0) {
        #pragma unroll
        for (int j = 0; j < 5; ++j)
            out[(size_t)n * C2 + l8 + 8 * j] = v[j] - mx - lg;
    }
}

extern "C" void kernel_launch(void* const* d_in, const int* in_sizes, int n_in,
                              void* d_out, int out_size, void* d_ws, size_t ws_size,
                              hipStream_t stream)
{
    const float* x     = (const float*)d_in[0];
    const int*   ei    = (const int*)  d_in[1];
    const float* W1l   = (const float*)d_in[2];
    const float* b1l   = (const float*)d_in[3];
    const float* W1r   = (const float*)d_in[4];
    const float* b1r   = (const float*)d_in[5];
    const float* att1  = (const float*)d_in[6];
    const float* bias1 = (const float*)d_in[7];
    const float* W2l   = (const float*)d_in[8];
    const float* b2l   = (const float*)d_in[9];
    const float* W2r   = (const float*)d_in[10];
    const float* b2r   = (const float*)d_in[11];
    const float* att2  = (const float*)d_in[12];
    const float* bias2 = (const float*)d_in[13];
    float* out = (float*)d_out;

    float* ws = (float*)d_ws;
    unsigned short* xl1 = (unsigned short*)ws;               // 12.8M bf16 (25.6 MB)
    unsigned short* xr1 = (unsigned short*)(ws + 6400000);   // 12.8M bf16 (doubles as h)
    unsigned short* xb  = (unsigned short*)(ws + 12800000);  // x in bf16 (ends at +19200000)
    int*   csr    = (int*)(ws + 19200000);                   // ELL: NODES*64 = 3.2M ints
    int*   cnt    = csr + CSRCAP;                            // NODES (real degree)
    unsigned short* Wt1 = (unsigned short*)(ws + 22500000);  // 512*256 bf16
    unsigned short* Wt2 = (unsigned short*)(ws + 22600000);  // 80*256 bf16
    unsigned short* h = xr1;                                 // layer-1 output (in place)
    float* h2l = ws;                                         // 2M f32 (over dead xl1)
    float* h2r = ws + 2000000;

    const int* srcRow = ei;
    const int* dstRow = ei + NEDGE;

    // ---- prep: memsets + ELL place+cvt + weight transposes (no scan chain) ----
    hipMemsetAsync(cnt, 0, NODES * sizeof(int), stream);
    hipMemsetAsync(csr, 0, CSRCAP * sizeof(int), stream);
    prep_a<<<NB_CNT + NB_CVT, 256, 0, stream>>>(srcRow, dstRow, cnt, csr, x, xb);
    prep_ww<<<512 + 80, 256, 0, stream>>>(W1l, W1r, Wt1, W2l, W2r, Wt2);

    // ---- layer 1 ----
    mfma_gemm<unsigned short, true><<<((NODES + GBM - 1) / GBM) * 4, 256, 0, stream>>>(
        xb, Wt1, b1l, b1r, xl1, xr1, NODES, 2 * C1, C1, 2);
    fused_l1<<<(NODES + 3) / 4, 256, 0, stream>>>(cnt, csr, xl1, xr1, att1, bias1, h);

    // ---- layer 2 ----
    mfma_gemm<float, false><<<(NODES + GBM - 1) / GBM, 256, 0, stream>>>(
        h, Wt2, b2l, b2r, h2l, h2r, NODES, 2 * C2, C2, 0);
    fused_l2<<<(NODES + 3) / 4, 256, 0, stream>>>(cnt, csr, h2l, h2r, att2, bias2, out);
}

// Round 26
// 181.839 us; speedup vs baseline: 1.7317x; 1.7317x over previous
//
#include <hip/hip_runtime.h>
#include <math.h>

#define NODES 50000
#define NEDGE 400000
#define ETOT  450000   // NEDGE + NODES self loops
#define DIN   256
#define C1    256      // heads*dh = 8*32
#define C2    40
#define CPAD  64                        // ELL row pitch (max degree ~25 for this graph)
#define CSRCAP (NODES * CPAD)           // 3.2M slots
#define NB_CNT ((ETOT + 255) / 256)     // 1758 place blocks
#define NB_CVT (NODES * DIN / 8 / 256)  // 6250 cvt blocks

typedef __attribute__((ext_vector_type(8))) short bfrag;
typedef __attribute__((ext_vector_type(4))) float facc;

#define GPTR(p) (const __attribute__((address_space(1))) unsigned int*)(p)
#define LPTR(p) (__attribute__((address_space(3))) unsigned int*)(p)

static __device__ __forceinline__ float bitsf(unsigned int x) {
    float f;
    __builtin_memcpy(&f, &x, 4);
    return f;
}
static __device__ __forceinline__ unsigned short f2bf(float f) {
    unsigned int x;
    __builtin_memcpy(&x, &f, 4);
    unsigned int r = x + 0x7fffu + ((x >> 16) & 1u);   // RNE
    return (unsigned short)(r >> 16);
}
static __device__ __forceinline__ float fexp2(float x) {
#if __has_builtin(__builtin_amdgcn_exp2f)
    return __builtin_amdgcn_exp2f(x);
#else
    return exp2f(x);
#endif
}

// ---------------- fused prep A: ELL place (count+scatter) + x f32->bf16 convert ----------------
__global__ __launch_bounds__(256)
void prep_a(const int* __restrict__ srcRow, const int* __restrict__ dstRow,
            int* __restrict__ cnt, int* __restrict__ csr,
            const float* __restrict__ x, unsigned short* __restrict__ xb)
{
    if (blockIdx.x < NB_CNT) {
        int e = blockIdx.x * 256 + threadIdx.x;
        if (e >= ETOT) return;
        int d, s;
        if (e < NEDGE) { d = dstRow[e]; s = srcRow[e]; }
        else           { d = e - NEDGE; s = d; }
        int slot = atomicAdd(&cnt[d], 1);
        csr[(d << 6) + slot] = s;
    } else {
        int i = (blockIdx.x - NB_CNT) * 256 + threadIdx.x;   // < NB_CVT*256 exactly
        const float4* p = (const float4*)x + (size_t)i * 2;
        float4 u0 = p[0], u1 = p[1];
        bfrag pk;
        pk[0] = (short)f2bf(u0.x); pk[1] = (short)f2bf(u0.y);
        pk[2] = (short)f2bf(u0.z); pk[3] = (short)f2bf(u0.w);
        pk[4] = (short)f2bf(u1.x); pk[5] = (short)f2bf(u1.y);
        pk[6] = (short)f2bf(u1.z); pk[7] = (short)f2bf(u1.w);
        *(bfrag*)(xb + (size_t)i * 8) = pk;
    }
}

// ---------------- fused prep W: both weight transposes ----------------
__global__ __launch_bounds__(256)
void prep_ww(const float* __restrict__ W1l, const float* __restrict__ W1r,
             unsigned short* __restrict__ Wt1,
             const float* __restrict__ W2l, const float* __restrict__ W2r,
             unsigned short* __restrict__ Wt2)
{
    if (blockIdx.x < 512) {
        const int idx = blockIdx.x * 256 + threadIdx.x;   // n*256 + k
        const int n = idx >> 8;
        const int k = idx & 255;
        float v = (n < C1) ? W1l[(size_t)k * C1 + n] : W1r[(size_t)k * C1 + (n - C1)];
        Wt1[idx] = f2bf(v);
    } else {
        const int idx = (blockIdx.x - 512) * 256 + threadIdx.x;
        const int n = idx >> 8;
        const int k = idx & 255;
        if (n >= 2 * C2) return;
        float v = (n < C2) ? W2l[(size_t)k * C2 + n] : W2r[(size_t)k * C2 + (n - C2)];
        Wt2[idx] = f2bf(v);
    }
}

// ---------------- MFMA dual GEMM: 3-buffer / 2-ahead pipeline, 1 barrier per K-step ----------------
#define GBM 128
#define GBN 128
#define GBK 32

template<typename OUTT, bool SWZ>
__global__ __launch_bounds__(256)
void mfma_gemm(const unsigned short* __restrict__ Ab, const unsigned short* __restrict__ Bt,
               const float* __restrict__ bl, const float* __restrict__ br,
               OUTT* __restrict__ Cl, OUTT* __restrict__ Cr,
               int M, int Nrows, int Nhalf, int nbnShift)
{
    __shared__ __align__(16) unsigned short As[3][GBM * GBK];
    __shared__ __align__(16) unsigned short Bs[3][GBN * GBK];

    const int tid  = threadIdx.x;
    const int lane = tid & 63;
    const int w    = tid >> 6;
    const int wr   = w >> 1;
    const int wc   = w & 1;

    int tile;
    if constexpr (SWZ) {
        const int nwg = gridDim.x;
        const int q = nwg >> 3, r = nwg & 7;
        const int xcd = blockIdx.x & 7;
        const int idx = blockIdx.x >> 3;
        tile = (xcd < r ? xcd * (q + 1) : r * (q + 1) + (xcd - r) * q) + idx;
    } else {
        tile = blockIdx.x;
    }
    const int bx   = tile >> nbnShift;
    const int by   = tile & ((1 << nbnShift) - 1);
    const int row0 = bx * GBM;
    const int col0 = by * GBN;

    facc acc[4][4];
    #pragma unroll
    for (int i = 0; i < 4; ++i)
        #pragma unroll
        for (int j = 0; j < 4; ++j) {
            facc z = {0.f, 0.f, 0.f, 0.f};
            acc[i][j] = z;
        }

    const int rA  = lane >> 2;
    const int kgA = (lane & 3) ^ ((rA >> 1) & 3);
    const int fr    = lane & 15;
    const int sRead = (lane >> 4) ^ ((fr >> 1) & 3);

    #define STAGE(bufi, k0)                                                     \
    {                                                                           \
        _Pragma("unroll")                                                       \
        for (int p = 0; p < 2; ++p) {                                           \
            const int chunk = p * 4 + w;                                        \
            const int r_loc = chunk * 16 + rA;                                  \
            const int ga = min(row0 + r_loc, M - 1);                            \
            __builtin_amdgcn_global_load_lds(                                   \
                GPTR(Ab + (size_t)ga * 256 + (k0) + kgA * 8),                   \
                LPTR(&As[bufi][chunk * 512]), 16, 0, 0);                        \
            const int gb = min(col0 + r_loc, Nrows - 1);                        \
            __builtin_amdgcn_global_load_lds(                                   \
                GPTR(Bt + (size_t)gb * 256 + (k0) + kgA * 8),                   \
                LPTR(&Bs[bufi][chunk * 512]), 16, 0, 0);                        \
        }                                                                       \
    }

    #define KSTEP(T, WSTR)                                                      \
    {                                                                           \
        asm volatile("s_waitcnt vmcnt(" WSTR ")" ::: "memory");                 \
        __builtin_amdgcn_s_barrier();                                           \
        __builtin_amdgcn_sched_barrier(0);                                      \
        constexpr int cur = (T) % 3;                                            \
        bfrag af[4], bfv[4];                                                    \
        _Pragma("unroll")                                                       \
        for (int mi = 0; mi < 4; ++mi)                                          \
            af[mi] = *(const bfrag*)(&As[cur][(wr * 64 + mi * 16 + fr) * 32 + sRead * 8]); \
        _Pragma("unroll")                                                       \
        for (int ni = 0; ni < 4; ++ni)                                          \
            bfv[ni] = *(const bfrag*)(&Bs[cur][(wc * 64 + ni * 16 + fr) * 32 + sRead * 8]); \
        if constexpr ((T) + 2 < 8) STAGE(((T) + 2) % 3, ((T) + 2) * GBK);       \
        _Pragma("unroll")                                                       \
        for (int mi = 0; mi < 4; ++mi)                                          \
            _Pragma("unroll")                                                   \
            for (int ni = 0; ni < 4; ++ni)                                      \
                acc[mi][ni] = __builtin_amdgcn_mfma_f32_16x16x32_bf16(          \
                    af[mi], bfv[ni], acc[mi][ni], 0, 0, 0);                     \
    }

    STAGE(0, 0 * GBK);
    STAGE(1, 1 * GBK);
    KSTEP(0, "4"); KSTEP(1, "4"); KSTEP(2, "4"); KSTEP(3, "4");
    KSTEP(4, "4"); KSTEP(5, "4"); KSTEP(6, "4"); KSTEP(7, "0");
    #undef KSTEP
    #undef STAGE

    #pragma unroll
    for (int mi = 0; mi < 4; ++mi) {
        const int rbase = row0 + wr * 64 + mi * 16 + ((lane >> 4) << 2);
        #pragma unroll
        for (int ni = 0; ni < 4; ++ni) {
            const int col = col0 + wc * 64 + ni * 16 + (lane & 15);
            #pragma unroll
            for (int rg = 0; rg < 4; ++rg) {
                int r = rbase + rg;
                if (r >= M) continue;
                float v = acc[mi][ni][rg];
                if (col < Nhalf) {
                    v += bl[col];
                    if constexpr (sizeof(OUTT) == 2)
                        Cl[(size_t)r * Nhalf + col] = (OUTT)f2bf(v);
                    else
                        Cl[(size_t)r * Nhalf + col] = (OUTT)v;
                } else if (col < 2 * Nhalf) {
                    int c2 = col - Nhalf;
                    v += br[c2];
                    if constexpr (sizeof(OUTT) == 2)
                        Cr[(size_t)r * Nhalf + c2] = (OUTT)f2bf(v);
                    else
                        Cr[(size_t)r * Nhalf + c2] = (OUTT)v;
                }
            }
        }
    }
}

// ---------------- fused layer 1: wave/node, 2 edges per wave (half-wave split) ----------------
// lane owns 8 channels (4 lanes per head); halves process disjoint edges; merged at end.
__global__ __launch_bounds__(256)
void fused_l1(const int* __restrict__ deg,
              const int* __restrict__ csr, const unsigned short* __restrict__ xl,
              const unsigned short* __restrict__ xr, const float* __restrict__ att,
              const float* __restrict__ bias, unsigned short* __restrict__ hout)
{
    const int lane = threadIdx.x & 63;
    const int n    = blockIdx.x * 4 + (threadIdx.x >> 6);
    if (n >= NODES) return;
    const int eh  = lane >> 5;    // edge half (0/1)
    const int l32 = lane & 31;
    const int c0  = l32 * 8;      // channel base (8 channels/lane, 4 lanes/head)

    const int a  = n << 6;        // ELL base
    const int dn = __builtin_amdgcn_readfirstlane(deg[n]);
    const int np = (dn + 3) & ~3;

    const float L2E = 1.4426950408889634f;
    const float MINIT = -1e30f, MMASK = -2e30f;   // finite sentinels (exp2 diff underflows to 0)

    float xrv[8];
    {
        const uint4 u = *(const uint4*)(xr + (size_t)n * C1 + c0);
        xrv[0] = bitsf(u.x << 16); xrv[1] = bitsf(u.x & 0xffff0000u);
        xrv[2] = bitsf(u.y << 16); xrv[3] = bitsf(u.y & 0xffff0000u);
        xrv[4] = bitsf(u.z << 16); xrv[5] = bitsf(u.z & 0xffff0000u);
        xrv[6] = bitsf(u.w << 16); xrv[7] = bitsf(u.w & 0xffff0000u);
    }
    float w6[8], w4[8];
    {
        const float4 wa = *(const float4*)(att + c0);
        const float4 wb = *(const float4*)(att + c0 + 4);
        const float wv[8] = {wa.x, wa.y, wa.z, wa.w, wb.x, wb.y, wb.z, wb.w};
        #pragma unroll
        for (int j = 0; j < 8; ++j) {
            w6[j] = wv[j] * (0.6f * L2E);
            w4[j] = wv[j] * (0.4f * L2E);
        }
    }

    float m = MINIT, d = 0.f;
    float acc[8] = {0.f, 0.f, 0.f, 0.f, 0.f, 0.f, 0.f, 0.f};

    // each half-lane loads its 2 edges' src (int2) + 2 row slices (uint4)
    #define LOADG(D0, D1, I)                                                     \
    {                                                                            \
        const int2 s2 = *(const int2*)(csr + a + (I) + 2 * eh);                  \
        D0 = *(const uint4*)(xl + (size_t)s2.x * C1 + c0);                       \
        D1 = *(const uint4*)(xl + (size_t)s2.y * C1 + c0);                       \
    }
    #define UNPACK(X, U)                                                         \
        X[0] = bitsf(U.x << 16); X[1] = bitsf(U.x & 0xffff0000u);                \
        X[2] = bitsf(U.y << 16); X[3] = bitsf(U.y & 0xffff0000u);                \
        X[4] = bitsf(U.z << 16); X[5] = bitsf(U.z & 0xffff0000u);                \
        X[6] = bitsf(U.w << 16); X[7] = bitsf(U.w & 0xffff0000u);

    uint4 R0, R1;
    LOADG(R0, R1, 0);

    for (int i = 0; i < np; i += 4) {
        uint4 Rn0, Rn1;
        LOADG(Rn0, Rn1, i + 4);   // indices <= i+4+3 <= 31 < CPAD; pads zeroed

        float x0[8], x1[8];
        UNPACK(x0, R0)
        UNPACK(x1, R1)

        float p0 = 0.f, p1 = 0.f;
        #pragma unroll
        for (int j = 0; j < 8; ++j) {
            const float v = x0[j] + xrv[j];
            p0 = fmaf(w6[j], v, p0);
            p0 = fmaf(w4[j], fabsf(v), p0);
        }
        #pragma unroll
        for (int j = 0; j < 8; ++j) {
            const float v = x1[j] + xrv[j];
            p1 = fmaf(w6[j], v, p1);
            p1 = fmaf(w4[j], fabsf(v), p1);
        }
        p0 += __shfl_xor(p0, 1); p0 += __shfl_xor(p0, 2);
        p1 += __shfl_xor(p1, 1); p1 += __shfl_xor(p1, 2);
        const int e0 = i + 2 * eh;
        p0 = (e0     < dn) ? p0 : MMASK;
        p1 = (e0 + 1 < dn) ? p1 : MMASK;

        const float pm = fmaxf(p0, p1);
        if (__any(pm > m + 8.f)) {
            float mN = fmaxf(m, p0);
            float sc = fexp2(m - mN);
            float wg = fexp2(p0 - mN);
            m = mN;
            d = fmaf(d, sc, wg);
            #pragma unroll
            for (int j = 0; j < 8; ++j) acc[j] = fmaf(wg, x0[j], acc[j] * sc);
            mN = fmaxf(m, p1);
            sc = fexp2(m - mN);
            wg = fexp2(p1 - mN);
            m = mN;
            d = fmaf(d, sc, wg);
            #pragma unroll
            for (int j = 0; j < 8; ++j) acc[j] = fmaf(wg, x1[j], acc[j] * sc);
        } else {
            const float wg0 = fexp2(p0 - m);
            const float wg1 = fexp2(p1 - m);
            d += wg0 + wg1;
            #pragma unroll
            for (int j = 0; j < 8; ++j)
                acc[j] = fmaf(wg1, x1[j], fmaf(wg0, x0[j], acc[j]));
        }

        R0 = Rn0; R1 = Rn1;
    }
    #undef LOADG
    #undef UNPACK

    // merge the two halves (same channels, disjoint edges)
    {
        const float mo = __shfl_xor(m, 32);
        const float mN = fmaxf(m, mo);
        const float sc = fexp2(m - mN);   // underflows to 0 for an all-masked half
        d *= sc;
        d += __shfl_xor(d, 32);
        #pragma unroll
        for (int j = 0; j < 8; ++j) {
            acc[j] *= sc;
            acc[j] += __shfl_xor(acc[j], 32);
        }
    }

    const float inv = 1.f / d;
    float vv[8];
    {
        const float4 ba = *(const float4*)(bias + c0);
        const float4 bb = *(const float4*)(bias + c0 + 4);
        const float bv[8] = {ba.x, ba.y, ba.z, ba.w, bb.x, bb.y, bb.z, bb.w};
        #pragma unroll
        for (int j = 0; j < 8; ++j) {
            float v = fmaf(acc[j], inv, bv[j]);
            vv[j] = v > 0.f ? v : (fexp2(v * L2E) - 1.f);
        }
    }
    if (eh == 0) {
        uint4 o;
        o.x = (unsigned int)f2bf(vv[0]) | ((unsigned int)f2bf(vv[1]) << 16);
        o.y = (unsigned int)f2bf(vv[2]) | ((unsigned int)f2bf(vv[3]) << 16);
        o.z = (unsigned int)f2bf(vv[4]) | ((unsigned int)f2bf(vv[5]) << 16);
        o.w = (unsigned int)f2bf(vv[6]) | ((unsigned int)f2bf(vv[7]) << 16);
        *(uint4*)(hout + (size_t)n * C1 + c0) = o;
    }
}

// ---------------- fused layer 2: 8-edge groups + prefetch, ELL base = n*64 ----------------
__global__ __launch_bounds__(256)
void fused_l2(const int* __restrict__ deg,
              const int* __restrict__ csr, const float* __restrict__ h2l,
              const float* __restrict__ h2r, const float* __restrict__ att,
              const float* __restrict__ bias, float* __restrict__ out)
{
    const int lane = threadIdx.x & 63;
    const int n    = blockIdx.x * 4 + (threadIdx.x >> 6);
    if (n >= NODES) return;
    const int l8 = lane & 7;
    const int g  = lane >> 3;

    const int a  = n << 6;   // ELL base
    const int dn = __builtin_amdgcn_readfirstlane(deg[n]);
    const float L2E = 1.4426950408889634f;

    float w6[5], w4[5], xr[5];
    #pragma unroll
    for (int j = 0; j < 5; ++j) {
        const int c = l8 + 8 * j;
        const float w = att[c];
        w6[j] = w * (0.6f * L2E);
        w4[j] = w * (0.4f * L2E);
        xr[j] = h2r[(size_t)n * C2 + c];
    }

    float m = -INFINITY, dl = 0.f;
    float acc[5] = {0.f, 0.f, 0.f, 0.f, 0.f};

    // prologue: load chunk 0
    float R[5];
    {
        const int src = csr[a + g];
        const float* row = h2l + (size_t)src * C2 + l8;
        #pragma unroll
        for (int j = 0; j < 5; ++j) R[j] = row[8 * j];
    }

    for (int c0 = 0; c0 < dn; c0 += 8) {
        // prefetch chunk c0+8 (pad slots zeroed; c0+8+g <= 40 < CPAD)
        float Rn[5];
        {
            const int nx = (c0 + 8 < dn) ? (c0 + 8) : c0;
            const int src = csr[a + nx + g];
            const float* row = h2l + (size_t)src * C2 + l8;
            #pragma unroll
            for (int j = 0; j < 5; ++j) Rn[j] = row[8 * j];
        }

        const int idx = c0 + g;
        float p = 0.f;
        #pragma unroll
        for (int j = 0; j < 5; ++j) {
            const float v = R[j] + xr[j];
            p = fmaf(w6[j], v, p);
            p = fmaf(w4[j], fabsf(v), p);
        }
        p += __shfl_xor(p, 1);
        p += __shfl_xor(p, 2);
        p += __shfl_xor(p, 4);
        if (idx >= dn) p = -INFINITY;

        if (__any(p > m + 8.f)) {
            float pm = p;
            pm = fmaxf(pm, __shfl_xor(pm, 8));
            pm = fmaxf(pm, __shfl_xor(pm, 16));
            pm = fmaxf(pm, __shfl_xor(pm, 32));
            const float mN = fmaxf(m, pm);
            const float sc = fexp2(m - mN);
            const float wg = fexp2(p - mN);
            m = mN;
            dl = fmaf(dl, sc, wg);
            #pragma unroll
            for (int j = 0; j < 5; ++j) acc[j] = fmaf(wg, R[j], acc[j] * sc);
        } else {
            const float wg = fexp2(p - m);
            dl += wg;
            #pragma unroll
            for (int j = 0; j < 5; ++j) acc[j] = fmaf(wg, R[j], acc[j]);
        }

        #pragma unroll
        for (int j = 0; j < 5; ++j) R[j] = Rn[j];
    }

    #pragma unroll
    for (int o = 8; o < 64; o <<= 1) {
        dl += __shfl_xor(dl, o);
        #pragma unroll
        for (int j = 0; j < 5; ++j) acc[j] += __shfl_xor(acc[j], o);
    }

    const float inv = 1.f / dl;
    float v[5];
    float mx = -INFINITY;
    #pragma unroll
    for (int j = 0; j < 5; ++j) {
        v[j] = fmaf(acc[j], inv, bias[l8 + 8 * j]);
        mx = fmaxf(mx, v[j]);
    }
    mx = fmaxf(mx, __shfl_xor(mx, 1));
    mx = fmaxf(mx, __shfl_xor(mx, 2));
    mx = fmaxf(mx, __shfl_xor(mx, 4));
    float s = 0.f;
    #pragma unroll
    for (int j = 0; j < 5; ++j) s += fexp2((v[j] - mx) * L2E);
    s += __shfl_xor(s, 1);
    s += __shfl_xor(s, 2);
    s += __shfl_xor(s, 4);
    const float lg = logf(s);
    if (g == 0) {
        #pragma unroll
        for (int j = 0; j < 5; ++j)
            out[(size_t)n * C2 + l8 + 8 * j] = v[j] - mx - lg;
    }
}

extern "C" void kernel_launch(void* const* d_in, const int* in_sizes, int n_in,
                              void* d_out, int out_size, void* d_ws, size_t ws_size,
                              hipStream_t stream)
{
    const float* x     = (const float*)d_in[0];
    const int*   ei    = (const int*)  d_in[1];
    const float* W1l   = (const float*)d_in[2];
    const float* b1l   = (const float*)d_in[3];
    const float* W1r   = (const float*)d_in[4];
    const float* b1r   = (const float*)d_in[5];
    const float* att1  = (const float*)d_in[6];
    const float* bias1 = (const float*)d_in[7];
    const float* W2l   = (const float*)d_in[8];
    const float* b2l   = (const float*)d_in[9];
    const float* W2r   = (const float*)d_in[10];
    const float* b2r   = (const float*)d_in[11];
    const float* att2  = (const float*)d_in[12];
    const float* bias2 = (const float*)d_in[13];
    float* out = (float*)d_out;

    float* ws = (float*)d_ws;
    unsigned short* xl1 = (unsigned short*)ws;               // 12.8M bf16 (25.6 MB)
    unsigned short* xr1 = (unsigned short*)(ws + 6400000);   // 12.8M bf16 (doubles as h)
    unsigned short* xb  = (unsigned short*)(ws + 12800000);  // x in bf16 (ends at +19200000)
    int*   csr    = (int*)(ws + 19200000);                   // ELL: NODES*64 = 3.2M ints
    int*   cnt    = csr + CSRCAP;                            // NODES (real degree)
    unsigned short* Wt1 = (unsigned short*)(ws + 22500000);  // 512*256 bf16
    unsigned short* Wt2 = (unsigned short*)(ws + 22600000);  // 80*256 bf16
    unsigned short* h = xr1;                                 // layer-1 output (in place)
    float* h2l = ws;                                         // 2M f32 (over dead xl1)
    float* h2r = ws + 2000000;

    const int* srcRow = ei;
    const int* dstRow = ei + NEDGE;

    // ---- prep: memsets + ELL place+cvt + weight transposes (no scan chain) ----
    hipMemsetAsync(cnt, 0, NODES * sizeof(int), stream);
    hipMemsetAsync(csr, 0, CSRCAP * sizeof(int), stream);
    prep_a<<<NB_CNT + NB_CVT, 256, 0, stream>>>(srcRow, dstRow, cnt, csr, x, xb);
    prep_ww<<<512 + 80, 256, 0, stream>>>(W1l, W1r, Wt1, W2l, W2r, Wt2);

    // ---- layer 1 ----
    mfma_gemm<unsigned short, true><<<((NODES + GBM - 1) / GBM) * 4, 256, 0, stream>>>(
        xb, Wt1, b1l, b1r, xl1, xr1, NODES, 2 * C1, C1, 2);
    fused_l1<<<(NODES + 3) / 4, 256, 0, stream>>>(cnt, csr, xl1, xr1, att1, bias1, h);

    // ---- layer 2 ----
    mfma_gemm<float, false><<<(NODES + GBM - 1) / GBM, 256, 0, stream>>>(
        h, Wt2, b2l, b2r, h2l, h2r, NODES, 2 * C2, C2, 0);
    fused_l2<<<(NODES + 3) / 4, 256, 0, stream>>>(cnt, csr, h2l, h2r, att2, bias2, out);
}